// Round 2
// baseline (4172.670 us; speedup 1.0000x reference)
//
#include <hip/hip_runtime.h>

#define NH    20000
#define NF    200000
#define DHOST 64
#define DFLOW 128
#define DHID  256
#define NE    2000000
#define NLAYER 2

// ---------------- small utils ----------------
__global__ void zero_k(int* __restrict__ p, int n) {
    int i = blockIdx.x * 256 + threadIdx.x;
    if (i < n) p[i] = 0;
}

// ---------------- CSR build ----------------
__global__ void count_k(const int* __restrict__ dst, int E, int* __restrict__ cnt) {
    int i = blockIdx.x * 256 + threadIdx.x;
    if (i < E) atomicAdd(&cnt[dst[i]], 1);
}

// exclusive scan of 1024-element chunks; block = 256 threads, 4 elems/thread
__global__ void scan1_k(const int* __restrict__ in, int n, int* __restrict__ out, int* __restrict__ bsum) {
    __shared__ int wsum[4];
    int b = blockIdx.x;
    int t = threadIdx.x;
    int lane = t & 63, wave = t >> 6;
    int idx = b * 1024 + t * 4;
    int v[4]; int s = 0;
#pragma unroll
    for (int i = 0; i < 4; ++i) { v[i] = (idx + i < n) ? in[idx + i] : 0; s += v[i]; }
    int inc = s;
#pragma unroll
    for (int off = 1; off < 64; off <<= 1) { int u = __shfl_up(inc, off); if (lane >= off) inc += u; }
    if (lane == 63) wsum[wave] = inc;
    __syncthreads();
    int woff = 0;
    for (int w = 0; w < wave; ++w) woff += wsum[w];
    int ex = woff + inc - s;
#pragma unroll
    for (int i = 0; i < 4; ++i) { if (idx + i < n) out[idx + i] = ex; ex += v[i]; }
    if (t == 255) bsum[b] = woff + inc;
}

// single-block exclusive scan of up to 256 block sums, in place
__global__ void scan2_k(int* __restrict__ bs, int nb) {
    __shared__ int wsum[4];
    int t = threadIdx.x, lane = t & 63, wave = t >> 6;
    int v = (t < nb) ? bs[t] : 0;
    int s = v;
#pragma unroll
    for (int off = 1; off < 64; off <<= 1) { int u = __shfl_up(s, off); if (lane >= off) s += u; }
    if (lane == 63) wsum[wave] = s;
    __syncthreads();
    int woff = 0;
    for (int w = 0; w < wave; ++w) woff += wsum[w];
    if (t < nb) bs[t] = woff + s - v;
}

// add block offsets, copy to cursor, write rowptr[n]
__global__ void scan3_k(int* __restrict__ rowptr, const int* __restrict__ bs, int n, int E, int* __restrict__ cursor) {
    int i = blockIdx.x * 256 + threadIdx.x;
    if (i < n) { int v = rowptr[i] + bs[i >> 10]; rowptr[i] = v; cursor[i] = v; }
    if (i == n) rowptr[n] = E;
}

__global__ void fill_k(const int* __restrict__ src, const int* __restrict__ dst, int E,
                       int* __restrict__ cursor, int* __restrict__ col) {
    int i = blockIdx.x * 256 + threadIdx.x;
    if (i < E) {
        int p = atomicAdd(&cursor[dst[i]], 1);
        col[p] = src[i];
    }
}

// ---------------- mean aggregation (CSR gather) ----------------
// one block (256 threads) per destination node; thread t owns feature dim t.
// rowptr is pre-offset by the caller; output rows are local (0..grid-1).
__global__ __launch_bounds__(256) void agg_mean(const float* __restrict__ srcFeat,
                                                const int* __restrict__ rowptr,
                                                const int* __restrict__ col,
                                                float* __restrict__ outp) {
    int d = blockIdx.x;
    int t = threadIdx.x;
    int beg = rowptr[d], end = rowptr[d + 1];
    float acc = 0.0f;
    for (int e = beg; e < end; ++e) {
        int s = col[e];
        acc += srcFeat[(size_t)s * DHID + t];
    }
    int deg = end - beg;
    float inv = 1.0f / (float)(deg > 0 ? deg : 1);
    outp[(size_t)d * DHID + t] = acc * inv;
}

// ---------------- tiled fp32 GEMM, N fixed at 256 ----------------
// BM=64, BN=256, BK=32, 256 threads, 64 outputs/thread (4 rows x 16 cols)
template<int K>
__device__ __forceinline__ void gemm_pass(const float* A, const float* __restrict__ W,
                                          int m0, int M, int tid, int ty, int tx,
                                          float (&acc)[4][16],
                                          float (*As)[33], float (*Ws)[256]) {
    for (int k0 = 0; k0 < K; k0 += 32) {
        // A tile: 64 rows x 32 cols = 512 float4
#pragma unroll
        for (int i = tid; i < 512; i += 256) {
            int r = i >> 3, c = (i & 7) << 2;
            int gr = m0 + r; if (gr >= M) gr = M - 1;
            const float4 v = *reinterpret_cast<const float4*>(A + (size_t)gr * K + k0 + c);
            As[r][c + 0] = v.x; As[r][c + 1] = v.y; As[r][c + 2] = v.z; As[r][c + 3] = v.w;
        }
        // W tile: rows k0..k0+32 of [K][256] -> contiguous 8192 floats
        const float4* wp = reinterpret_cast<const float4*>(W + (size_t)k0 * 256);
        float4* wl = reinterpret_cast<float4*>(&Ws[0][0]);
#pragma unroll
        for (int i = tid; i < 2048; i += 256) wl[i] = wp[i];
        __syncthreads();
#pragma unroll
        for (int k = 0; k < 32; ++k) {
            float a0 = As[ty +  0][k];
            float a1 = As[ty + 16][k];
            float a2 = As[ty + 32][k];
            float a3 = As[ty + 48][k];
#pragma unroll
            for (int j = 0; j < 4; ++j) {
                const float4 w = *reinterpret_cast<const float4*>(&Ws[k][(tx + 16 * j) << 2]);
                acc[0][j*4+0] += a0 * w.x; acc[0][j*4+1] += a0 * w.y; acc[0][j*4+2] += a0 * w.z; acc[0][j*4+3] += a0 * w.w;
                acc[1][j*4+0] += a1 * w.x; acc[1][j*4+1] += a1 * w.y; acc[1][j*4+2] += a1 * w.z; acc[1][j*4+3] += a1 * w.w;
                acc[2][j*4+0] += a2 * w.x; acc[2][j*4+1] += a2 * w.y; acc[2][j*4+2] += a2 * w.z; acc[2][j*4+3] += a2 * w.w;
                acc[3][j*4+0] += a3 * w.x; acc[3][j*4+1] += a3 * w.y; acc[3][j*4+2] += a3 * w.z; acc[3][j*4+3] += a3 * w.w;
            }
        }
        __syncthreads();
    }
}

template<int ACT>  // 0 none, 1 relu, 2 leaky(0.01)
__device__ __forceinline__ void gemm_epilogue(float (&acc)[4][16], const float* __restrict__ bias,
                                              float* outp, int m0, int M, int ty, int tx) {
#pragma unroll
    for (int r = 0; r < 4; ++r) {
        int gr = m0 + ty + r * 16;
        if (gr >= M) continue;
#pragma unroll
        for (int j = 0; j < 4; ++j) {
            int c = (tx + 16 * j) << 2;
            const float4 b = *reinterpret_cast<const float4*>(bias + c);
            float4 v;
            v.x = acc[r][j*4+0] + b.x;
            v.y = acc[r][j*4+1] + b.y;
            v.z = acc[r][j*4+2] + b.z;
            v.w = acc[r][j*4+3] + b.w;
            if (ACT == 1) {
                v.x = fmaxf(v.x, 0.0f); v.y = fmaxf(v.y, 0.0f);
                v.z = fmaxf(v.z, 0.0f); v.w = fmaxf(v.w, 0.0f);
            } else if (ACT == 2) {
                v.x = v.x > 0.0f ? v.x : 0.01f * v.x;
                v.y = v.y > 0.0f ? v.y : 0.01f * v.y;
                v.z = v.z > 0.0f ? v.z : 0.01f * v.z;
                v.w = v.w > 0.0f ? v.w : 0.01f * v.w;
            }
            *reinterpret_cast<float4*>(outp + (size_t)gr * 256 + c) = v;
        }
    }
}

template<int K1, int ACT>
__global__ __launch_bounds__(256) void gemm1(const float* __restrict__ A1, const float* __restrict__ W1,
                                             const float* __restrict__ bias, float* outp, int M) {
    __shared__ float As[64][33];
    __shared__ float Ws[32][256];
    const int tid = threadIdx.x;
    const int m0 = blockIdx.x * 64;
    const int ty = tid >> 4, tx = tid & 15;
    float acc[4][16];
#pragma unroll
    for (int r = 0; r < 4; ++r)
#pragma unroll
        for (int c = 0; c < 16; ++c) acc[r][c] = 0.0f;
    gemm_pass<K1>(A1, W1, m0, M, tid, ty, tx, acc, As, Ws);
    gemm_epilogue<ACT>(acc, bias, outp, m0, M, ty, tx);
}

// fused SAGE: out = act(A1@W1 + bias + A2@W2); out may alias A2 (each block
// reads only its own 64 rows, and all reads precede the epilogue stores)
template<int ACT>
__global__ __launch_bounds__(256) void gemm2(const float* A1, const float* __restrict__ W1,
                                             const float* __restrict__ bias,
                                             const float* A2, const float* __restrict__ W2,
                                             float* outp, int M) {
    __shared__ float As[64][33];
    __shared__ float Ws[32][256];
    const int tid = threadIdx.x;
    const int m0 = blockIdx.x * 64;
    const int ty = tid >> 4, tx = tid & 15;
    float acc[4][16];
#pragma unroll
    for (int r = 0; r < 4; ++r)
#pragma unroll
        for (int c = 0; c < 16; ++c) acc[r][c] = 0.0f;
    gemm_pass<DHID>(A1, W1, m0, M, tid, ty, tx, acc, As, Ws);
    gemm_pass<DHID>(A2, W2, m0, M, tid, ty, tx, acc, As, Ws);
    gemm_epilogue<ACT>(acc, bias, outp, m0, M, ty, tx);
}

// final projection [M,256] @ [256,2] + b ; one wave per row
__global__ __launch_bounds__(256) void out_gemm(const float* __restrict__ f, const float* __restrict__ W,
                                                const float* __restrict__ b, float* __restrict__ outp, int M) {
    int wave = threadIdx.x >> 6, lane = threadIdx.x & 63;
    int row = blockIdx.x * 4 + wave;
    if (row >= M) return;
    float a0 = 0.0f, a1 = 0.0f;
#pragma unroll
    for (int q = 0; q < 4; ++q) {
        int i = lane + q * 64;
        float v = f[(size_t)row * 256 + i];
        a0 += v * W[i * 2 + 0];
        a1 += v * W[i * 2 + 1];
    }
#pragma unroll
    for (int off = 32; off > 0; off >>= 1) {
        a0 += __shfl_down(a0, off);
        a1 += __shfl_down(a1, off);
    }
    if (lane == 0) {
        outp[(size_t)row * 2 + 0] = a0 + b[0];
        outp[(size_t)row * 2 + 1] = a1 + b[1];
    }
}

extern "C" void kernel_launch(void* const* d_in, const int* in_sizes, int n_in,
                              void* d_out, int out_size, void* d_ws, size_t ws_size,
                              hipStream_t stream) {
    const float* x_host  = (const float*)d_in[0];
    const float* x_flow  = (const float*)d_in[1];
    const int*   hf_src  = (const int*)d_in[2];
    const int*   hf_dst  = (const int*)d_in[3];
    const int*   fh_src  = (const int*)d_in[4];
    const int*   fh_dst  = (const int*)d_in[5];
    const float* host_W  = (const float*)d_in[6];
    const float* host_b  = (const float*)d_in[7];
    const float* flow_W  = (const float*)d_in[8];
    const float* flow_b  = (const float*)d_in[9];
    const float* Wl_hf   = (const float*)d_in[10];
    const float* bl_hf   = (const float*)d_in[11];
    const float* Wr_hf   = (const float*)d_in[12];
    const float* Wl_fh   = (const float*)d_in[13];
    const float* bl_fh   = (const float*)d_in[14];
    const float* Wr_fh   = (const float*)d_in[15];
    const float* lin_W   = (const float*)d_in[16];
    const float* lin_b   = (const float*)d_in[17];

    char* ws = (char*)d_ws;
    size_t off = 0;
    auto alloc = [&](size_t bytes) -> char* {
        char* p = ws + off;
        off += (bytes + 255) & ~(size_t)255;
        return p;
    };
    // fixed-footprint buffers (~265 MB total)
    float* F      = (float*)alloc((size_t)NF * DHID * 4);       // flow features, updated in place
    float* H      = (float*)alloc((size_t)NH * DHID * 4);       // host features, updated in place
    float* AggH   = (float*)alloc((size_t)NH * DHID * 4);       // fh-aggregation result
    int*   rp_hf  = (int*)alloc((size_t)(NF + 1) * 4);
    int*   cur_hf = (int*)alloc((size_t)NF * 4);
    int*   col_hf = (int*)alloc((size_t)NE * 4);
    int*   bs_hf  = (int*)alloc(256 * 4);
    int*   rp_fh  = (int*)alloc((size_t)(NH + 1) * 4);
    int*   cur_fh = (int*)alloc((size_t)NH * 4);
    int*   col_fh = (int*)alloc((size_t)NE * 4);
    int*   bs_fh  = (int*)alloc(256 * 4);

    // adaptive chunk buffer for the flow-side aggregation
    size_t avail = (ws_size > off) ? (ws_size - off) : 0;
    long long ch = (long long)(avail / ((size_t)DHID * 4)) - 64;
    if (ch < 64) ch = 64;
    if (ch > NF) ch = NF;
    int CH = (int)(ch & ~63LL);
    if (CH < 64) CH = 64;
    float* AggC = (float*)alloc((size_t)CH * DHID * 4);

    const int nbE   = (NE + 255) / 256;
    const int nb_hf = (NF + 1023) / 1024;
    const int nb_fh = (NH + 1023) / 1024;

    // ---- CSR build (reused by both layers) ----
    zero_k<<<(NF + 255) / 256, 256, 0, stream>>>(cur_hf, NF);
    zero_k<<<(NH + 255) / 256, 256, 0, stream>>>(cur_fh, NH);
    count_k<<<nbE, 256, 0, stream>>>(hf_dst, NE, cur_hf);
    count_k<<<nbE, 256, 0, stream>>>(fh_dst, NE, cur_fh);
    scan1_k<<<nb_hf, 256, 0, stream>>>(cur_hf, NF, rp_hf, bs_hf);
    scan1_k<<<nb_fh, 256, 0, stream>>>(cur_fh, NH, rp_fh, bs_fh);
    scan2_k<<<1, 256, 0, stream>>>(bs_hf, nb_hf);
    scan2_k<<<1, 256, 0, stream>>>(bs_fh, nb_fh);
    scan3_k<<<(NF + 256) / 256, 256, 0, stream>>>(rp_hf, bs_hf, NF, NE, cur_hf);
    scan3_k<<<(NH + 256) / 256, 256, 0, stream>>>(rp_fh, bs_fh, NH, NE, cur_fh);
    fill_k<<<nbE, 256, 0, stream>>>(hf_src, hf_dst, NE, cur_hf, col_hf);
    fill_k<<<nbE, 256, 0, stream>>>(fh_src, fh_dst, NE, cur_fh, col_fh);

    // ---- input projections ----
    gemm1<DHOST, 1><<<(NH + 63) / 64, 256, 0, stream>>>(x_host, host_W, host_b, H, NH);
    gemm1<DFLOW, 1><<<(NF + 63) / 64, 256, 0, stream>>>(x_flow, flow_W, flow_b, F, NF);

    // ---- SAGE layers (in-place feature updates; both sides consume OLD h,f) ----
    for (int i = 0; i < NLAYER; ++i) {
        const float* wl_hf = Wl_hf + (size_t)i * DHID * DHID;
        const float* wr_hf = Wr_hf + (size_t)i * DHID * DHID;
        const float* wl_fh = Wl_fh + (size_t)i * DHID * DHID;
        const float* wr_fh = Wr_fh + (size_t)i * DHID * DHID;
        const float* b_hf  = bl_hf + (size_t)i * DHID;
        const float* b_fh  = bl_fh + (size_t)i * DHID;

        // 1) host-side aggregation from OLD f (must precede any F overwrite)
        agg_mean<<<NH, 256, 0, stream>>>(F, rp_fh, col_fh, AggH);

        // 2) flow update, chunked: agg from OLD h, then in-place gemm on F rows
        for (int c0 = 0; c0 < NF; c0 += CH) {
            int rows = NF - c0; if (rows > CH) rows = CH;
            agg_mean<<<rows, 256, 0, stream>>>(H, rp_hf + c0, col_hf, AggC);
            gemm2<2><<<(rows + 63) / 64, 256, 0, stream>>>(AggC, wl_hf, b_hf,
                                                           F + (size_t)c0 * DHID, wr_hf,
                                                           F + (size_t)c0 * DHID, rows);
        }

        // 3) host update, in-place on H (uses OLD h as root)
        gemm2<2><<<(NH + 63) / 64, 256, 0, stream>>>(AggH, wl_fh, b_fh, H, wr_fh, H, NH);
    }

    // ---- output head ----
    out_gemm<<<(NF + 3) / 4, 256, 0, stream>>>(F, lin_W, lin_b, (float*)d_out, NF);
}

// Round 3
// 1709.720 us; speedup vs baseline: 2.4406x; 2.4406x over previous
//
#include <hip/hip_runtime.h>

#define NH    20000
#define NF    200000
#define DHOST 64
#define DFLOW 128
#define DHID  256
#define NE    2000000
#define NLAYER 2

typedef __attribute__((ext_vector_type(8))) short s16x8;
typedef __attribute__((ext_vector_type(4))) float f32x4;

__device__ __forceinline__ unsigned short f2bf(float x) {
    unsigned u = __builtin_bit_cast(unsigned, x);
    unsigned r = (u + 0x7fffu + ((u >> 16) & 1u)) >> 16;
    return (unsigned short)r;
}
__device__ __forceinline__ float bf2f(unsigned short h) {
    unsigned u = ((unsigned)h) << 16;
    return __builtin_bit_cast(float, u);
}

// ---------------- small utils ----------------
__global__ void zero_k(int* __restrict__ p, int n) {
    int i = blockIdx.x * 256 + threadIdx.x;
    if (i < n) p[i] = 0;
}

// float -> bf16 elementwise (n multiple of 4)
__global__ __launch_bounds__(256) void cvt_bf16_k(const float* __restrict__ in, unsigned short* __restrict__ out, int n4) {
    int i = blockIdx.x * 256 + threadIdx.x;
    if (i < n4) {
        float4 v = *reinterpret_cast<const float4*>(in + (size_t)i * 4);
        ushort4 o;
        o.x = f2bf(v.x); o.y = f2bf(v.y); o.z = f2bf(v.z); o.w = f2bf(v.w);
        *reinterpret_cast<ushort4*>(out + (size_t)i * 4) = o;
    }
}

// W [K][256] f32 -> Wt [256][K] bf16 ; grid (8, K/32), block 256
__global__ __launch_bounds__(256) void tpose_k(const float* __restrict__ W, unsigned short* __restrict__ Wt, int K) {
    __shared__ float T[32][33];
    int bx = blockIdx.x, by = blockIdx.y;
    int tx = threadIdx.x & 31, ty = threadIdx.x >> 5;
#pragma unroll
    for (int i = 0; i < 4; ++i) {
        int k = by * 32 + ty + i * 8;
        T[ty + i * 8][tx] = W[(size_t)k * 256 + bx * 32 + tx];
    }
    __syncthreads();
#pragma unroll
    for (int i = 0; i < 4; ++i) {
        int n = bx * 32 + ty + i * 8;
        Wt[(size_t)n * K + by * 32 + tx] = f2bf(T[tx][ty + i * 8]);
    }
}

// ---------------- CSR build ----------------
__global__ void count_k(const int* __restrict__ dst, int E, int* __restrict__ cnt) {
    int i = blockIdx.x * 256 + threadIdx.x;
    if (i < E) atomicAdd(&cnt[dst[i]], 1);
}

__global__ void scan1_k(const int* __restrict__ in, int n, int* __restrict__ out, int* __restrict__ bsum) {
    __shared__ int wsum[4];
    int b = blockIdx.x;
    int t = threadIdx.x;
    int lane = t & 63, wave = t >> 6;
    int idx = b * 1024 + t * 4;
    int v[4]; int s = 0;
#pragma unroll
    for (int i = 0; i < 4; ++i) { v[i] = (idx + i < n) ? in[idx + i] : 0; s += v[i]; }
    int inc = s;
#pragma unroll
    for (int off = 1; off < 64; off <<= 1) { int u = __shfl_up(inc, off); if (lane >= off) inc += u; }
    if (lane == 63) wsum[wave] = inc;
    __syncthreads();
    int woff = 0;
    for (int w = 0; w < wave; ++w) woff += wsum[w];
    int ex = woff + inc - s;
#pragma unroll
    for (int i = 0; i < 4; ++i) { if (idx + i < n) out[idx + i] = ex; ex += v[i]; }
    if (t == 255) bsum[b] = woff + inc;
}

__global__ void scan2_k(int* __restrict__ bs, int nb) {
    __shared__ int wsum[4];
    int t = threadIdx.x, lane = t & 63, wave = t >> 6;
    int v = (t < nb) ? bs[t] : 0;
    int s = v;
#pragma unroll
    for (int off = 1; off < 64; off <<= 1) { int u = __shfl_up(s, off); if (lane >= off) s += u; }
    if (lane == 63) wsum[wave] = s;
    __syncthreads();
    int woff = 0;
    for (int w = 0; w < wave; ++w) woff += wsum[w];
    if (t < nb) bs[t] = woff + s - v;
}

__global__ void scan3_k(int* __restrict__ rowptr, const int* __restrict__ bs, int n, int E, int* __restrict__ cursor) {
    int i = blockIdx.x * 256 + threadIdx.x;
    if (i < n) { int v = rowptr[i] + bs[i >> 10]; rowptr[i] = v; cursor[i] = v; }
    if (i == n) rowptr[n] = E;
}

__global__ void fill_k(const int* __restrict__ src, const int* __restrict__ dst, int E,
                       int* __restrict__ cursor, int* __restrict__ col) {
    int i = blockIdx.x * 256 + threadIdx.x;
    if (i < E) {
        int p = atomicAdd(&cursor[dst[i]], 1);
        col[p] = src[i];
    }
}

// ---------------- mean aggregation (CSR gather, bf16) ----------------
// one wave per destination node; lane owns dims lane*4..lane*4+3
__global__ __launch_bounds__(256) void agg_bf16(const unsigned short* __restrict__ srcFeat,
                                                const int* __restrict__ rowptr,
                                                const int* __restrict__ col,
                                                unsigned short* __restrict__ outp, int n) {
    int w = (blockIdx.x << 2) + (threadIdx.x >> 6);
    if (w >= n) return;
    int lane = threadIdx.x & 63;
    int beg = rowptr[w], end = rowptr[w + 1];
    float a0 = 0.f, a1 = 0.f, a2 = 0.f, a3 = 0.f;
    const unsigned short* base = srcFeat + lane * 4;
    for (int e = beg; e < end; ++e) {
        int s = col[e];
        ushort4 v = *reinterpret_cast<const ushort4*>(base + (size_t)s * DHID);
        a0 += bf2f(v.x); a1 += bf2f(v.y); a2 += bf2f(v.z); a3 += bf2f(v.w);
    }
    int deg = end - beg;
    float inv = 1.0f / (float)(deg > 0 ? deg : 1);
    ushort4 o;
    o.x = f2bf(a0 * inv); o.y = f2bf(a1 * inv); o.z = f2bf(a2 * inv); o.w = f2bf(a3 * inv);
    *reinterpret_cast<ushort4*>(outp + (size_t)w * DHID + lane * 4) = o;
}

// ---------------- MFMA bf16 GEMM, N fixed at 256 ----------------
// BM=128, BN=256, BK=64, 512 threads (8 waves as 2x4), wave tile 64x64.
__device__ __forceinline__ unsigned swz(unsigned r, unsigned cb) {
    return r * 128u + (cb ^ ((r & 7u) << 4));
}

template<int KP>
__device__ __forceinline__ void mfma_pass(const unsigned short* A, const unsigned short* Wt,
                                          int m0, int M, int tid, int lane, int wr, int wc,
                                          f32x4 (&acc)[4][4], char* AsB, char* BsB) {
    for (int k0 = 0; k0 < KP; k0 += 64) {
        __syncthreads();
        // stage A tile: 128 rows x 64 cols bf16 = 1024 x 16B units
#pragma unroll
        for (int i = 0; i < 2; ++i) {
            int u = tid + i * 512;
            int r = u >> 3, c = u & 7;
            int gr = m0 + r; if (gr >= M) gr = M - 1;
            s16x8 v = *reinterpret_cast<const s16x8*>(A + (size_t)gr * KP + k0 + c * 8);
            *reinterpret_cast<s16x8*>(AsB + swz((unsigned)r, (unsigned)(c * 16))) = v;
        }
        // stage B tile: 256 rows (n) x 64 cols (k) = 2048 x 16B units
#pragma unroll
        for (int i = 0; i < 4; ++i) {
            int u = tid + i * 512;
            int nn = u >> 3, c = u & 7;
            s16x8 v = *reinterpret_cast<const s16x8*>(Wt + (size_t)nn * KP + k0 + c * 8);
            *reinterpret_cast<s16x8*>(BsB + swz((unsigned)nn, (unsigned)(c * 16))) = v;
        }
        __syncthreads();
#pragma unroll
        for (int kk = 0; kk < 2; ++kk) {
            s16x8 ar[4], br[4];
            unsigned colb = (unsigned)(kk * 64 + (lane >> 4) * 16);
#pragma unroll
            for (int mf = 0; mf < 4; ++mf)
                ar[mf] = *reinterpret_cast<const s16x8*>(AsB + swz((unsigned)(wr * 64 + mf * 16 + (lane & 15)), colb));
#pragma unroll
            for (int nf = 0; nf < 4; ++nf)
                br[nf] = *reinterpret_cast<const s16x8*>(BsB + swz((unsigned)(wc * 64 + nf * 16 + (lane & 15)), colb));
#pragma unroll
            for (int mf = 0; mf < 4; ++mf)
#pragma unroll
                for (int nf = 0; nf < 4; ++nf)
                    acc[mf][nf] = __builtin_amdgcn_mfma_f32_16x16x32_bf16(ar[mf], br[nf], acc[mf][nf], 0, 0, 0);
        }
    }
}

// out = act(A1@W1t^T + bias [+ A2@W2t^T]); out may alias A1/A2 rows of this block
template<int K1, int ACT, int FUSE>  // ACT: 0 none, 1 relu, 2 leaky(0.01)
__global__ __launch_bounds__(512) void mgemm(const unsigned short* A1, const unsigned short* W1t,
                                             const float* __restrict__ bias,
                                             const unsigned short* A2, const unsigned short* W2t,
                                             unsigned short* outp, int M) {
    __shared__ char AsB[128 * 64 * 2];
    __shared__ char BsB[256 * 64 * 2];
    const int tid = threadIdx.x;
    const int lane = tid & 63, wave = tid >> 6;
    const int wr = wave >> 2, wc = wave & 3;
    const int m0 = blockIdx.x * 128;
    f32x4 acc[4][4];
#pragma unroll
    for (int a = 0; a < 4; ++a)
#pragma unroll
        for (int b = 0; b < 4; ++b) acc[a][b] = (f32x4)0.0f;

    mfma_pass<K1>(A1, W1t, m0, M, tid, lane, wr, wc, acc, AsB, BsB);
    if (FUSE) mfma_pass<DHID>(A2, W2t, m0, M, tid, lane, wr, wc, acc, AsB, BsB);

    // epilogue: C layout col=lane&15, row=(lane>>4)*4+j  (per 16x16 fragment)
    const int col0 = wc * 64 + (lane & 15);
    float bc[4];
#pragma unroll
    for (int nf = 0; nf < 4; ++nf) bc[nf] = bias[col0 + nf * 16];
#pragma unroll
    for (int mf = 0; mf < 4; ++mf) {
        int row = m0 + wr * 64 + mf * 16 + (lane >> 4) * 4;
#pragma unroll
        for (int j = 0; j < 4; ++j) {
            if (row + j < M) {
#pragma unroll
                for (int nf = 0; nf < 4; ++nf) {
                    float v = acc[mf][nf][j] + bc[nf];
                    if (ACT == 1) v = fmaxf(v, 0.0f);
                    else if (ACT == 2) v = v > 0.0f ? v : 0.01f * v;
                    outp[(size_t)(row + j) * DHID + col0 + nf * 16] = f2bf(v);
                }
            }
        }
    }
}

// final projection [M,256]bf16 @ [256,2]f32 + b ; one wave per row
__global__ __launch_bounds__(256) void head_k(const unsigned short* __restrict__ f, const float* __restrict__ W,
                                              const float* __restrict__ b, float* __restrict__ outp, int M) {
    int row = blockIdx.x * 4 + (threadIdx.x >> 6);
    if (row >= M) return;
    int lane = threadIdx.x & 63;
    ushort4 v = *reinterpret_cast<const ushort4*>(f + (size_t)row * DHID + lane * 4);
    float4 w0 = *reinterpret_cast<const float4*>(W + lane * 8);
    float4 w1 = *reinterpret_cast<const float4*>(W + lane * 8 + 4);
    float a0 = bf2f(v.x) * w0.x + bf2f(v.y) * w0.z + bf2f(v.z) * w1.x + bf2f(v.w) * w1.z;
    float a1 = bf2f(v.x) * w0.y + bf2f(v.y) * w0.w + bf2f(v.z) * w1.y + bf2f(v.w) * w1.w;
#pragma unroll
    for (int off = 32; off > 0; off >>= 1) {
        a0 += __shfl_down(a0, off);
        a1 += __shfl_down(a1, off);
    }
    if (lane == 0) {
        outp[(size_t)row * 2 + 0] = a0 + b[0];
        outp[(size_t)row * 2 + 1] = a1 + b[1];
    }
}

extern "C" void kernel_launch(void* const* d_in, const int* in_sizes, int n_in,
                              void* d_out, int out_size, void* d_ws, size_t ws_size,
                              hipStream_t stream) {
    const float* x_host  = (const float*)d_in[0];
    const float* x_flow  = (const float*)d_in[1];
    const int*   hf_src  = (const int*)d_in[2];
    const int*   hf_dst  = (const int*)d_in[3];
    const int*   fh_src  = (const int*)d_in[4];
    const int*   fh_dst  = (const int*)d_in[5];
    const float* host_W  = (const float*)d_in[6];
    const float* host_b  = (const float*)d_in[7];
    const float* flow_W  = (const float*)d_in[8];
    const float* flow_b  = (const float*)d_in[9];
    const float* Wl_hf   = (const float*)d_in[10];
    const float* bl_hf   = (const float*)d_in[11];
    const float* Wr_hf   = (const float*)d_in[12];
    const float* Wl_fh   = (const float*)d_in[13];
    const float* bl_fh   = (const float*)d_in[14];
    const float* Wr_fh   = (const float*)d_in[15];
    const float* lin_W   = (const float*)d_in[16];
    const float* lin_b   = (const float*)d_in[17];

    char* ws = (char*)d_ws;
    size_t off = 0;
    auto alloc = [&](size_t bytes) -> char* {
        char* p = ws + off;
        off += (bytes + 255) & ~(size_t)255;
        return p;
    };
    typedef unsigned short u16;
    // bf16 feature buffers
    u16* F     = (u16*)alloc((size_t)NF * DHID * 2);   // 102.4 MB
    u16* H     = (u16*)alloc((size_t)NH * DHID * 2);   // 10.2 MB
    u16* AggH  = (u16*)alloc((size_t)NH * DHID * 2);   // 10.2 MB
    u16* Xf    = (u16*)alloc((size_t)NF * DFLOW * 2);  // 51.2 MB
    u16* Xh    = (u16*)alloc((size_t)NH * DHOST * 2);  // 2.6 MB
    // transposed bf16 weights
    u16* hostWt = (u16*)alloc((size_t)DHID * DHOST * 2);
    u16* flowWt = (u16*)alloc((size_t)DHID * DFLOW * 2);
    u16* WlhfT  = (u16*)alloc((size_t)NLAYER * DHID * DHID * 2);
    u16* WrhfT  = (u16*)alloc((size_t)NLAYER * DHID * DHID * 2);
    u16* WlfhT  = (u16*)alloc((size_t)NLAYER * DHID * DHID * 2);
    u16* WrfhT  = (u16*)alloc((size_t)NLAYER * DHID * DHID * 2);
    // CSR
    int* rp_hf  = (int*)alloc((size_t)(NF + 1) * 4);
    int* cur_hf = (int*)alloc((size_t)NF * 4);
    int* col_hf = (int*)alloc((size_t)NE * 4);
    int* bs_hf  = (int*)alloc(256 * 4);
    int* rp_fh  = (int*)alloc((size_t)(NH + 1) * 4);
    int* cur_fh = (int*)alloc((size_t)NH * 4);
    int* col_fh = (int*)alloc((size_t)NE * 4);
    int* bs_fh  = (int*)alloc(256 * 4);

    // adaptive chunk for flow-side aggregation output (bf16)
    size_t avail = (ws_size > off) ? (ws_size - off) : 0;
    long long ch = (long long)(avail / ((size_t)DHID * 2)) - 128;
    if (ch < 128) ch = 128;
    if (ch > NF) ch = NF;
    int CH = (int)(ch & ~127LL);
    if (CH < 128) CH = 128;
    u16* AggC = (u16*)alloc((size_t)CH * DHID * 2);

    const int nbE   = (NE + 255) / 256;
    const int nb_hf = (NF + 1023) / 1024;
    const int nb_fh = (NH + 1023) / 1024;

    // ---- CSR build ----
    zero_k<<<(NF + 255) / 256, 256, 0, stream>>>(cur_hf, NF);
    zero_k<<<(NH + 255) / 256, 256, 0, stream>>>(cur_fh, NH);
    count_k<<<nbE, 256, 0, stream>>>(hf_dst, NE, cur_hf);
    count_k<<<nbE, 256, 0, stream>>>(fh_dst, NE, cur_fh);
    scan1_k<<<nb_hf, 256, 0, stream>>>(cur_hf, NF, rp_hf, bs_hf);
    scan1_k<<<nb_fh, 256, 0, stream>>>(cur_fh, NH, rp_fh, bs_fh);
    scan2_k<<<1, 256, 0, stream>>>(bs_hf, nb_hf);
    scan2_k<<<1, 256, 0, stream>>>(bs_fh, nb_fh);
    scan3_k<<<(NF + 256) / 256, 256, 0, stream>>>(rp_hf, bs_hf, NF, NE, cur_hf);
    scan3_k<<<(NH + 256) / 256, 256, 0, stream>>>(rp_fh, bs_fh, NH, NE, cur_fh);
    fill_k<<<nbE, 256, 0, stream>>>(hf_src, hf_dst, NE, cur_hf, col_hf);
    fill_k<<<nbE, 256, 0, stream>>>(fh_src, fh_dst, NE, cur_fh, col_fh);

    // ---- convert inputs / weights to bf16 ----
    cvt_bf16_k<<<(NH * DHOST / 4 + 255) / 256, 256, 0, stream>>>(x_host, Xh, NH * DHOST / 4);
    cvt_bf16_k<<<(NF * DFLOW / 4 + 255) / 256, 256, 0, stream>>>(x_flow, Xf, NF * DFLOW / 4);
    tpose_k<<<dim3(8, DHOST / 32), 256, 0, stream>>>(host_W, hostWt, DHOST);
    tpose_k<<<dim3(8, DFLOW / 32), 256, 0, stream>>>(flow_W, flowWt, DFLOW);
    for (int i = 0; i < NLAYER; ++i) {
        size_t wo = (size_t)i * DHID * DHID;
        tpose_k<<<dim3(8, 8), 256, 0, stream>>>(Wl_hf + wo, WlhfT + wo, DHID);
        tpose_k<<<dim3(8, 8), 256, 0, stream>>>(Wr_hf + wo, WrhfT + wo, DHID);
        tpose_k<<<dim3(8, 8), 256, 0, stream>>>(Wl_fh + wo, WlfhT + wo, DHID);
        tpose_k<<<dim3(8, 8), 256, 0, stream>>>(Wr_fh + wo, WrfhT + wo, DHID);
    }

    // ---- input projections (relu) ----
    mgemm<DHOST, 1, 0><<<(NH + 127) / 128, 512, 0, stream>>>(Xh, hostWt, host_b, Xh, hostWt, H, NH);
    mgemm<DFLOW, 1, 0><<<(NF + 127) / 128, 512, 0, stream>>>(Xf, flowWt, flow_b, Xf, flowWt, F, NF);

    // ---- SAGE layers (in-place feature updates; both sides consume OLD h,f) ----
    for (int i = 0; i < NLAYER; ++i) {
        const u16* wl_hf = WlhfT + (size_t)i * DHID * DHID;
        const u16* wr_hf = WrhfT + (size_t)i * DHID * DHID;
        const u16* wl_fh = WlfhT + (size_t)i * DHID * DHID;
        const u16* wr_fh = WrfhT + (size_t)i * DHID * DHID;
        const float* b_hf = bl_hf + (size_t)i * DHID;
        const float* b_fh = bl_fh + (size_t)i * DHID;

        // 1) host-side aggregation from OLD f (must precede any F overwrite)
        agg_bf16<<<(NH + 3) / 4, 256, 0, stream>>>(F, rp_fh, col_fh, AggH, NH);

        // 2) flow update, chunked: agg from OLD h, then in-place fused gemm on F rows
        for (int c0 = 0; c0 < NF; c0 += CH) {
            int rows = NF - c0; if (rows > CH) rows = CH;
            agg_bf16<<<(rows + 3) / 4, 256, 0, stream>>>(H, rp_hf + c0, col_hf, AggC, rows);
            mgemm<DHID, 2, 1><<<(rows + 127) / 128, 512, 0, stream>>>(AggC, wl_hf, b_hf,
                                                                      F + (size_t)c0 * DHID, wr_hf,
                                                                      F + (size_t)c0 * DHID, rows);
        }

        // 3) host update, in-place on H (uses OLD h as root)
        mgemm<DHID, 2, 1><<<(NH + 127) / 128, 512, 0, stream>>>(AggH, wl_fh, b_fh, H, wr_fh, H, NH);
    }

    // ---- output head ----
    head_k<<<(NF + 3) / 4, 256, 0, stream>>>(F, lin_W, lin_b, (float*)d_out, NF);
}

// Round 4
// 1363.514 us; speedup vs baseline: 3.0602x; 1.2539x over previous
//
#include <hip/hip_runtime.h>

#define NH    20000
#define NF    200000
#define DHOST 64
#define DFLOW 128
#define DHID  256
#define NE    2000000
#define NLAYER 2

typedef __attribute__((ext_vector_type(8))) short s16x8;
typedef __attribute__((ext_vector_type(4))) float f32x4;

__device__ __forceinline__ unsigned short f2bf(float x) {
    unsigned u = __builtin_bit_cast(unsigned, x);
    unsigned r = (u + 0x7fffu + ((u >> 16) & 1u)) >> 16;
    return (unsigned short)r;
}
__device__ __forceinline__ float bf2f(unsigned short h) {
    unsigned u = ((unsigned)h) << 16;
    return __builtin_bit_cast(float, u);
}

typedef const __attribute__((address_space(1))) unsigned int guint;
typedef __attribute__((address_space(3))) unsigned int luint;
__device__ __forceinline__ void gld16(const void* g, void* l) {
    __builtin_amdgcn_global_load_lds((guint*)g, (luint*)l, 16, 0, 0);
}

// ---------------- small utils ----------------
__global__ void zero_k(int* __restrict__ p, int n) {
    int i = blockIdx.x * 256 + threadIdx.x;
    if (i < n) p[i] = 0;
}

__global__ __launch_bounds__(256) void cvt_bf16_k(const float* __restrict__ in, unsigned short* __restrict__ out, int n4) {
    int i = blockIdx.x * 256 + threadIdx.x;
    if (i < n4) {
        float4 v = *reinterpret_cast<const float4*>(in + (size_t)i * 4);
        ushort4 o;
        o.x = f2bf(v.x); o.y = f2bf(v.y); o.z = f2bf(v.z); o.w = f2bf(v.w);
        *reinterpret_cast<ushort4*>(out + (size_t)i * 4) = o;
    }
}

// W [K][256] f32 -> Wt [256][K] bf16 ; grid (8, K/32), block 256
__global__ __launch_bounds__(256) void tpose_k(const float* __restrict__ W, unsigned short* __restrict__ Wt, int K) {
    __shared__ float T[32][33];
    int bx = blockIdx.x, by = blockIdx.y;
    int tx = threadIdx.x & 31, ty = threadIdx.x >> 5;
#pragma unroll
    for (int i = 0; i < 4; ++i) {
        int k = by * 32 + ty + i * 8;
        T[ty + i * 8][tx] = W[(size_t)k * 256 + bx * 32 + tx];
    }
    __syncthreads();
#pragma unroll
    for (int i = 0; i < 4; ++i) {
        int n = bx * 32 + ty + i * 8;
        Wt[(size_t)n * K + by * 32 + tx] = f2bf(T[tx][ty + i * 8]);
    }
}

// ---------------- CSR build ----------------
__global__ void count_k(const int* __restrict__ dst, int E, int* __restrict__ cnt) {
    int i = blockIdx.x * 256 + threadIdx.x;
    if (i < E) atomicAdd(&cnt[dst[i]], 1);
}

__global__ void scan1_k(const int* __restrict__ in, int n, int* __restrict__ out, int* __restrict__ bsum) {
    __shared__ int wsum[4];
    int b = blockIdx.x;
    int t = threadIdx.x;
    int lane = t & 63, wave = t >> 6;
    int idx = b * 1024 + t * 4;
    int v[4]; int s = 0;
#pragma unroll
    for (int i = 0; i < 4; ++i) { v[i] = (idx + i < n) ? in[idx + i] : 0; s += v[i]; }
    int inc = s;
#pragma unroll
    for (int off = 1; off < 64; off <<= 1) { int u = __shfl_up(inc, off); if (lane >= off) inc += u; }
    if (lane == 63) wsum[wave] = inc;
    __syncthreads();
    int woff = 0;
    for (int w = 0; w < wave; ++w) woff += wsum[w];
    int ex = woff + inc - s;
#pragma unroll
    for (int i = 0; i < 4; ++i) { if (idx + i < n) out[idx + i] = ex; ex += v[i]; }
    if (t == 255) bsum[b] = woff + inc;
}

__global__ void scan2_k(int* __restrict__ bs, int nb) {
    __shared__ int wsum[4];
    int t = threadIdx.x, lane = t & 63, wave = t >> 6;
    int v = (t < nb) ? bs[t] : 0;
    int s = v;
#pragma unroll
    for (int off = 1; off < 64; off <<= 1) { int u = __shfl_up(s, off); if (lane >= off) s += u; }
    if (lane == 63) wsum[wave] = s;
    __syncthreads();
    int woff = 0;
    for (int w = 0; w < wave; ++w) woff += wsum[w];
    if (t < nb) bs[t] = woff + s - v;
}

__global__ void scan3_k(int* __restrict__ rowptr, const int* __restrict__ bs, int n, int E, int* __restrict__ cursor) {
    int i = blockIdx.x * 256 + threadIdx.x;
    if (i < n) { int v = rowptr[i] + bs[i >> 10]; rowptr[i] = v; cursor[i] = v; }
    if (i == n) rowptr[n] = E;
}

__global__ void fill_k(const int* __restrict__ src, const int* __restrict__ dst, int E,
                       int* __restrict__ cursor, int* __restrict__ col) {
    int i = blockIdx.x * 256 + threadIdx.x;
    if (i < E) {
        int p = atomicAdd(&cursor[dst[i]], 1);
        col[p] = src[i];
    }
}

// ---------------- mean aggregation (CSR gather, bf16, MLP version) ----------------
// one wave per dst node, split into two 32-lane halves; half h handles edges
// beg+h, beg+h+2, ... ; lane covers dims l5*8..l5*8+7 (16 B); 4x unroll.
__global__ __launch_bounds__(256) void agg_bf16(const unsigned short* __restrict__ srcFeat,
                                                const int* __restrict__ rowptr,
                                                const int* __restrict__ col,
                                                unsigned short* __restrict__ outp, int n) {
    int w = (blockIdx.x << 2) + (threadIdx.x >> 6);
    if (w >= n) return;
    int lane = threadIdx.x & 63;
    int half = lane >> 5, l5 = lane & 31;
    int beg = rowptr[w], end = rowptr[w + 1];
    float a[8];
#pragma unroll
    for (int j = 0; j < 8; ++j) a[j] = 0.0f;
    const unsigned short* base = srcFeat + l5 * 8;
    int i = beg + half;
    for (; i + 6 < end; i += 8) {
        int c0 = col[i], c1 = col[i + 2], c2 = col[i + 4], c3 = col[i + 6];
        s16x8 v0 = *reinterpret_cast<const s16x8*>(base + (size_t)c0 * DHID);
        s16x8 v1 = *reinterpret_cast<const s16x8*>(base + (size_t)c1 * DHID);
        s16x8 v2 = *reinterpret_cast<const s16x8*>(base + (size_t)c2 * DHID);
        s16x8 v3 = *reinterpret_cast<const s16x8*>(base + (size_t)c3 * DHID);
#pragma unroll
        for (int j = 0; j < 8; ++j)
            a[j] += bf2f((unsigned short)v0[j]) + bf2f((unsigned short)v1[j])
                  + bf2f((unsigned short)v2[j]) + bf2f((unsigned short)v3[j]);
    }
    for (; i < end; i += 2) {
        int c = col[i];
        s16x8 v = *reinterpret_cast<const s16x8*>(base + (size_t)c * DHID);
#pragma unroll
        for (int j = 0; j < 8; ++j) a[j] += bf2f((unsigned short)v[j]);
    }
    // combine the two halves
#pragma unroll
    for (int j = 0; j < 8; ++j) a[j] += __shfl_xor(a[j], 32);
    int deg = end - beg;
    float inv = 1.0f / (float)(deg > 0 ? deg : 1);
    if (half == 0) {
        s16x8 o;
#pragma unroll
        for (int j = 0; j < 8; ++j) o[j] = (short)f2bf(a[j] * inv);
        *reinterpret_cast<s16x8*>(outp + (size_t)w * DHID + l5 * 8) = o;
    }
}

// ---------------- MFMA bf16 GEMM, N fixed at 256 ----------------
// BM=128, BN=256, BK=64, 512 threads (8 waves as 2x4), wave tile 64x64.
// LDS layout: linear rows of 128 B, content column-granule-swizzled via
// pre-swizzled global source (granule g holds global granule g^(r&7)).
__device__ __forceinline__ unsigned swz(unsigned r, unsigned cb) {
    return r * 128u + (cb ^ ((r & 7u) << 4));
}

template<int KP>
__device__ __forceinline__ void mfma_pass(const unsigned short* A, const unsigned short* Wt,
                                          int m0, int M, int tid, int lane, int wr, int wc,
                                          f32x4 (&acc)[4][4], char* AsB, char* BsB) {
    const int wave = tid >> 6;
    for (int k0 = 0; k0 < KP; k0 += 64) {
        __syncthreads();
        // stage A tile: 128 rows x 64 cols bf16 (16 KB = 16 x 1KB wave units)
#pragma unroll
        for (int i = 0; i < 2; ++i) {
            int u = wave * 2 + i;
            int r = u * 8 + (lane >> 3);
            int gr = m0 + r; if (gr >= M) gr = M - 1;
            int gs = (lane & 7) ^ (r & 7);
            gld16(A + (size_t)gr * KP + k0 + gs * 8, AsB + u * 1024);
        }
        // stage B tile: 256 rows x 64 cols bf16 (32 KB = 32 x 1KB wave units)
#pragma unroll
        for (int i = 0; i < 4; ++i) {
            int u = wave * 4 + i;
            int nn = u * 8 + (lane >> 3);
            int gs = (lane & 7) ^ (nn & 7);
            gld16(Wt + (size_t)nn * KP + k0 + gs * 8, BsB + u * 1024);
        }
        __syncthreads();
#pragma unroll
        for (int kk = 0; kk < 2; ++kk) {
            s16x8 ar[4], br[4];
            unsigned colb = (unsigned)(kk * 64 + (lane >> 4) * 16);
#pragma unroll
            for (int mf = 0; mf < 4; ++mf)
                ar[mf] = *reinterpret_cast<const s16x8*>(AsB + swz((unsigned)(wr * 64 + mf * 16 + (lane & 15)), colb));
#pragma unroll
            for (int nf = 0; nf < 4; ++nf)
                br[nf] = *reinterpret_cast<const s16x8*>(BsB + swz((unsigned)(wc * 64 + nf * 16 + (lane & 15)), colb));
#pragma unroll
            for (int mf = 0; mf < 4; ++mf)
#pragma unroll
                for (int nf = 0; nf < 4; ++nf)
                    acc[mf][nf] = __builtin_amdgcn_mfma_f32_16x16x32_bf16(ar[mf], br[nf], acc[mf][nf], 0, 0, 0);
        }
    }
}

// out = act(A1@W1t^T + bias [+ A2@W2t^T]); out may alias A1/A2 rows of this block
template<int K1, int ACT, int FUSE>  // ACT: 0 none, 1 relu, 2 leaky(0.01)
__global__ __launch_bounds__(512) void mgemm(const unsigned short* A1, const unsigned short* W1t,
                                             const float* __restrict__ bias,
                                             const unsigned short* A2, const unsigned short* W2t,
                                             unsigned short* outp, int M) {
    __shared__ char AsB[128 * 64 * 2];
    __shared__ char BsB[256 * 64 * 2];
    const int tid = threadIdx.x;
    const int lane = tid & 63, wave = tid >> 6;
    const int wr = wave >> 2, wc = wave & 3;
    const int m0 = blockIdx.x * 128;
    f32x4 acc[4][4];
#pragma unroll
    for (int a = 0; a < 4; ++a)
#pragma unroll
        for (int b = 0; b < 4; ++b) acc[a][b] = (f32x4)0.0f;

    mfma_pass<K1>(A1, W1t, m0, M, tid, lane, wr, wc, acc, AsB, BsB);
    if (FUSE) mfma_pass<DHID>(A2, W2t, m0, M, tid, lane, wr, wc, acc, AsB, BsB);

    // epilogue: C layout col=lane&15, row=(lane>>4)*4+j  (per 16x16 fragment)
    const int col0 = wc * 64 + (lane & 15);
    float bc[4];
#pragma unroll
    for (int nf = 0; nf < 4; ++nf) bc[nf] = bias[col0 + nf * 16];
#pragma unroll
    for (int mf = 0; mf < 4; ++mf) {
        int row = m0 + wr * 64 + mf * 16 + (lane >> 4) * 4;
#pragma unroll
        for (int j = 0; j < 4; ++j) {
            if (row + j < M) {
#pragma unroll
                for (int nf = 0; nf < 4; ++nf) {
                    float v = acc[mf][nf][j] + bc[nf];
                    if (ACT == 1) v = fmaxf(v, 0.0f);
                    else if (ACT == 2) v = v > 0.0f ? v : 0.01f * v;
                    outp[(size_t)(row + j) * DHID + col0 + nf * 16] = f2bf(v);
                }
            }
        }
    }
}

// final projection [M,256]bf16 @ [256,2]f32 + b ; one wave per row
__global__ __launch_bounds__(256) void head_k(const unsigned short* __restrict__ f, const float* __restrict__ W,
                                              const float* __restrict__ b, float* __restrict__ outp, int M) {
    int row = blockIdx.x * 4 + (threadIdx.x >> 6);
    if (row >= M) return;
    int lane = threadIdx.x & 63;
    ushort4 v = *reinterpret_cast<const ushort4*>(f + (size_t)row * DHID + lane * 4);
    float4 w0 = *reinterpret_cast<const float4*>(W + lane * 8);
    float4 w1 = *reinterpret_cast<const float4*>(W + lane * 8 + 4);
    float a0 = bf2f(v.x) * w0.x + bf2f(v.y) * w0.z + bf2f(v.z) * w1.x + bf2f(v.w) * w1.z;
    float a1 = bf2f(v.x) * w0.y + bf2f(v.y) * w0.w + bf2f(v.z) * w1.y + bf2f(v.w) * w1.w;
#pragma unroll
    for (int off = 32; off > 0; off >>= 1) {
        a0 += __shfl_down(a0, off);
        a1 += __shfl_down(a1, off);
    }
    if (lane == 0) {
        outp[(size_t)row * 2 + 0] = a0 + b[0];
        outp[(size_t)row * 2 + 1] = a1 + b[1];
    }
}

extern "C" void kernel_launch(void* const* d_in, const int* in_sizes, int n_in,
                              void* d_out, int out_size, void* d_ws, size_t ws_size,
                              hipStream_t stream) {
    const float* x_host  = (const float*)d_in[0];
    const float* x_flow  = (const float*)d_in[1];
    const int*   hf_src  = (const int*)d_in[2];
    const int*   hf_dst  = (const int*)d_in[3];
    const int*   fh_src  = (const int*)d_in[4];
    const int*   fh_dst  = (const int*)d_in[5];
    const float* host_W  = (const float*)d_in[6];
    const float* host_b  = (const float*)d_in[7];
    const float* flow_W  = (const float*)d_in[8];
    const float* flow_b  = (const float*)d_in[9];
    const float* Wl_hf   = (const float*)d_in[10];
    const float* bl_hf   = (const float*)d_in[11];
    const float* Wr_hf   = (const float*)d_in[12];
    const float* Wl_fh   = (const float*)d_in[13];
    const float* bl_fh   = (const float*)d_in[14];
    const float* Wr_fh   = (const float*)d_in[15];
    const float* lin_W   = (const float*)d_in[16];
    const float* lin_b   = (const float*)d_in[17];

    char* ws = (char*)d_ws;
    size_t off = 0;
    auto alloc = [&](size_t bytes) -> char* {
        char* p = ws + off;
        off += (bytes + 255) & ~(size_t)255;
        return p;
    };
    typedef unsigned short u16;
    u16* F     = (u16*)alloc((size_t)NF * DHID * 2);
    u16* H     = (u16*)alloc((size_t)NH * DHID * 2);
    u16* AggH  = (u16*)alloc((size_t)NH * DHID * 2);
    u16* Xf    = (u16*)alloc((size_t)NF * DFLOW * 2);
    u16* Xh    = (u16*)alloc((size_t)NH * DHOST * 2);
    u16* hostWt = (u16*)alloc((size_t)DHID * DHOST * 2);
    u16* flowWt = (u16*)alloc((size_t)DHID * DFLOW * 2);
    u16* WlhfT  = (u16*)alloc((size_t)NLAYER * DHID * DHID * 2);
    u16* WrhfT  = (u16*)alloc((size_t)NLAYER * DHID * DHID * 2);
    u16* WlfhT  = (u16*)alloc((size_t)NLAYER * DHID * DHID * 2);
    u16* WrfhT  = (u16*)alloc((size_t)NLAYER * DHID * DHID * 2);
    int* rp_hf  = (int*)alloc((size_t)(NF + 1) * 4);
    int* cur_hf = (int*)alloc((size_t)NF * 4);
    int* col_hf = (int*)alloc((size_t)NE * 4);
    int* bs_hf  = (int*)alloc(256 * 4);
    int* rp_fh  = (int*)alloc((size_t)(NH + 1) * 4);
    int* cur_fh = (int*)alloc((size_t)NH * 4);
    int* col_fh = (int*)alloc((size_t)NE * 4);
    int* bs_fh  = (int*)alloc(256 * 4);

    size_t avail = (ws_size > off) ? (ws_size - off) : 0;
    long long ch = (long long)(avail / ((size_t)DHID * 2)) - 128;
    if (ch < 128) ch = 128;
    if (ch > NF) ch = NF;
    int CH = (int)(ch & ~127LL);
    if (CH < 128) CH = 128;
    u16* AggC = (u16*)alloc((size_t)CH * DHID * 2);

    const int nbE   = (NE + 255) / 256;
    const int nb_hf = (NF + 1023) / 1024;
    const int nb_fh = (NH + 1023) / 1024;

    // ---- CSR build ----
    zero_k<<<(NF + 255) / 256, 256, 0, stream>>>(cur_hf, NF);
    zero_k<<<(NH + 255) / 256, 256, 0, stream>>>(cur_fh, NH);
    count_k<<<nbE, 256, 0, stream>>>(hf_dst, NE, cur_hf);
    count_k<<<nbE, 256, 0, stream>>>(fh_dst, NE, cur_fh);
    scan1_k<<<nb_hf, 256, 0, stream>>>(cur_hf, NF, rp_hf, bs_hf);
    scan1_k<<<nb_fh, 256, 0, stream>>>(cur_fh, NH, rp_fh, bs_fh);
    scan2_k<<<1, 256, 0, stream>>>(bs_hf, nb_hf);
    scan2_k<<<1, 256, 0, stream>>>(bs_fh, nb_fh);
    scan3_k<<<(NF + 256) / 256, 256, 0, stream>>>(rp_hf, bs_hf, NF, NE, cur_hf);
    scan3_k<<<(NH + 256) / 256, 256, 0, stream>>>(rp_fh, bs_fh, NH, NE, cur_fh);
    fill_k<<<nbE, 256, 0, stream>>>(hf_src, hf_dst, NE, cur_hf, col_hf);
    fill_k<<<nbE, 256, 0, stream>>>(fh_src, fh_dst, NE, cur_fh, col_fh);

    // ---- convert inputs / weights to bf16 ----
    cvt_bf16_k<<<(NH * DHOST / 4 + 255) / 256, 256, 0, stream>>>(x_host, Xh, NH * DHOST / 4);
    cvt_bf16_k<<<(NF * DFLOW / 4 + 255) / 256, 256, 0, stream>>>(x_flow, Xf, NF * DFLOW / 4);
    tpose_k<<<dim3(8, DHOST / 32), 256, 0, stream>>>(host_W, hostWt, DHOST);
    tpose_k<<<dim3(8, DFLOW / 32), 256, 0, stream>>>(flow_W, flowWt, DFLOW);
    for (int i = 0; i < NLAYER; ++i) {
        size_t wo = (size_t)i * DHID * DHID;
        tpose_k<<<dim3(8, 8), 256, 0, stream>>>(Wl_hf + wo, WlhfT + wo, DHID);
        tpose_k<<<dim3(8, 8), 256, 0, stream>>>(Wr_hf + wo, WrhfT + wo, DHID);
        tpose_k<<<dim3(8, 8), 256, 0, stream>>>(Wl_fh + wo, WlfhT + wo, DHID);
        tpose_k<<<dim3(8, 8), 256, 0, stream>>>(Wr_fh + wo, WrfhT + wo, DHID);
    }

    // ---- input projections (relu) ----
    mgemm<DHOST, 1, 0><<<(NH + 127) / 128, 512, 0, stream>>>(Xh, hostWt, host_b, Xh, hostWt, H, NH);
    mgemm<DFLOW, 1, 0><<<(NF + 127) / 128, 512, 0, stream>>>(Xf, flowWt, flow_b, Xf, flowWt, F, NF);

    // ---- SAGE layers (in-place feature updates; both sides consume OLD h,f) ----
    for (int i = 0; i < NLAYER; ++i) {
        const u16* wl_hf = WlhfT + (size_t)i * DHID * DHID;
        const u16* wr_hf = WrhfT + (size_t)i * DHID * DHID;
        const u16* wl_fh = WlfhT + (size_t)i * DHID * DHID;
        const u16* wr_fh = WrfhT + (size_t)i * DHID * DHID;
        const float* b_hf = bl_hf + (size_t)i * DHID;
        const float* b_fh = bl_fh + (size_t)i * DHID;

        // 1) host-side aggregation from OLD f (must precede any F overwrite)
        agg_bf16<<<(NH + 3) / 4, 256, 0, stream>>>(F, rp_fh, col_fh, AggH, NH);

        // 2) flow update, chunked: agg from OLD h, then in-place fused gemm on F rows
        for (int c0 = 0; c0 < NF; c0 += CH) {
            int rows = NF - c0; if (rows > CH) rows = CH;
            agg_bf16<<<(rows + 3) / 4, 256, 0, stream>>>(H, rp_hf + c0, col_hf, AggC, rows);
            mgemm<DHID, 2, 1><<<(rows + 127) / 128, 512, 0, stream>>>(AggC, wl_hf, b_hf,
                                                                      F + (size_t)c0 * DHID, wr_hf,
                                                                      F + (size_t)c0 * DHID, rows);
        }

        // 3) host update, in-place on H (uses OLD h as root)
        mgemm<DHID, 2, 1><<<(NH + 127) / 128, 512, 0, stream>>>(AggH, wl_fh, b_fh, H, wr_fh, H, NH);
    }

    // ---- output head ----
    head_k<<<(NF + 3) / 4, 256, 0, stream>>>(F, lin_W, lin_b, (float*)d_out, NF);
}

// Round 5
// 1110.457 us; speedup vs baseline: 3.7576x; 1.2279x over previous
//
#include <hip/hip_runtime.h>

#define NH    20000
#define NF    200000
#define DHOST 64
#define DFLOW 128
#define DHID  256
#define NE    2000000
#define NLAYER 2

typedef __attribute__((ext_vector_type(8))) short s16x8;
typedef __attribute__((ext_vector_type(4))) float f32x4;

__device__ __forceinline__ unsigned short f2bf(float x) {
    unsigned u = __builtin_bit_cast(unsigned, x);
    unsigned r = (u + 0x7fffu + ((u >> 16) & 1u)) >> 16;
    return (unsigned short)r;
}
__device__ __forceinline__ float bf2f(unsigned short h) {
    unsigned u = ((unsigned)h) << 16;
    return __builtin_bit_cast(float, u);
}

typedef const __attribute__((address_space(1))) unsigned int guint;
typedef __attribute__((address_space(3))) unsigned int luint;
__device__ __forceinline__ void gld16(const void* g, void* l) {
    __builtin_amdgcn_global_load_lds((guint*)g, (luint*)l, 16, 0, 0);
}

// ---------------- small utils ----------------
__global__ void zero_k(int* __restrict__ p, int n) {
    int i = blockIdx.x * 256 + threadIdx.x;
    if (i < n) p[i] = 0;
}

__global__ __launch_bounds__(256) void cvt_bf16_k(const float* __restrict__ in, unsigned short* __restrict__ out, int n4) {
    int i = blockIdx.x * 256 + threadIdx.x;
    if (i < n4) {
        float4 v = *reinterpret_cast<const float4*>(in + (size_t)i * 4);
        ushort4 o;
        o.x = f2bf(v.x); o.y = f2bf(v.y); o.z = f2bf(v.z); o.w = f2bf(v.w);
        *reinterpret_cast<ushort4*>(out + (size_t)i * 4) = o;
    }
}

// W [K][256] f32 -> Wt [256][K] bf16 ; grid (8, K/32), block 256
__global__ __launch_bounds__(256) void tpose_k(const float* __restrict__ W, unsigned short* __restrict__ Wt, int K) {
    __shared__ float T[32][33];
    int bx = blockIdx.x, by = blockIdx.y;
    int tx = threadIdx.x & 31, ty = threadIdx.x >> 5;
#pragma unroll
    for (int i = 0; i < 4; ++i) {
        int k = by * 32 + ty + i * 8;
        T[ty + i * 8][tx] = W[(size_t)k * 256 + bx * 32 + tx];
    }
    __syncthreads();
#pragma unroll
    for (int i = 0; i < 4; ++i) {
        int n = bx * 32 + ty + i * 8;
        Wt[(size_t)n * K + by * 32 + tx] = f2bf(T[tx][ty + i * 8]);
    }
}

// exclusive scan, single block (n <= 1024), 256 threads x 4
__global__ void scan1_k(const int* __restrict__ in, int n, int* __restrict__ out, int* __restrict__ bsum) {
    __shared__ int wsum[4];
    int t = threadIdx.x;
    int lane = t & 63, wave = t >> 6;
    int idx = blockIdx.x * 1024 + t * 4;
    int v[4]; int s = 0;
#pragma unroll
    for (int i = 0; i < 4; ++i) { v[i] = (idx + i < n) ? in[idx + i] : 0; s += v[i]; }
    int inc = s;
#pragma unroll
    for (int off = 1; off < 64; off <<= 1) { int u = __shfl_up(inc, off); if (lane >= off) inc += u; }
    if (lane == 63) wsum[wave] = inc;
    __syncthreads();
    int woff = 0;
    for (int w = 0; w < wave; ++w) woff += wsum[w];
    int ex = woff + inc - s;
#pragma unroll
    for (int i = 0; i < 4; ++i) { if (idx + i < n) out[idx + i] = ex; ex += v[i]; }
    if (t == 255) bsum[blockIdx.x] = woff + inc;
}

// ---------------- bucketed CSR build ----------------
// pass A: global bucket histogram (LDS-staged)
template<int SH, int NBKT>
__global__ __launch_bounds__(256) void histA(const int* __restrict__ dst, int E, int* __restrict__ gbh) {
    __shared__ int lh[NBKT];
    for (int b = threadIdx.x; b < NBKT; b += 256) lh[b] = 0;
    __syncthreads();
#pragma unroll
    for (int k = 0; k < 8; ++k) {
        int i = blockIdx.x * 2048 + k * 256 + threadIdx.x;
        if (i < E) atomicAdd(&lh[dst[i] >> SH], 1);
    }
    __syncthreads();
    for (int b = threadIdx.x; b < NBKT; b += 256) if (lh[b]) atomicAdd(&gbh[b], lh[b]);
}

// cursors = bucket offsets; also append E sentinel
__global__ void initcur_k(int* __restrict__ bko, int* __restrict__ gcur, int nbkt, int E) {
    int i = blockIdx.x * 256 + threadIdx.x;
    if (i < nbkt) gcur[i] = bko[i];
    if (i == nbkt) bko[nbkt] = E;
}

// pass C: bin edges into bucket-grouped (src,dst) pairs; one reservation per (block,bucket)
template<int SH, int NBKT, int TILE>
__global__ __launch_bounds__(256) void binpass(const int* __restrict__ src, const int* __restrict__ dst, int E,
                                               int* __restrict__ gcur, int2* __restrict__ pairs) {
    __shared__ int lh[NBKT], resv[NBKT], lc[NBKT];
    const int tid = threadIdx.x;
    const int e0 = blockIdx.x * TILE;
    for (int b = tid; b < NBKT; b += 256) { lh[b] = 0; lc[b] = 0; }
    __syncthreads();
#pragma unroll 4
    for (int k = 0; k < TILE / 256; ++k) {
        int i = e0 + k * 256 + tid;
        if (i < E) atomicAdd(&lh[dst[i] >> SH], 1);
    }
    __syncthreads();
    for (int b = tid; b < NBKT; b += 256) if (lh[b]) resv[b] = atomicAdd(&gcur[b], lh[b]);
    __syncthreads();
#pragma unroll 4
    for (int k = 0; k < TILE / 256; ++k) {
        int i = e0 + k * 256 + tid;
        if (i < E) {
            int d = dst[i];
            int b = d >> SH;
            int p = resv[b] + atomicAdd(&lc[b], 1);
            pairs[p] = make_int2(src[i], d);
        }
    }
}

// pass D: one block per bucket -> per-node rowptr + fully sorted col
template<int SH, int NPB>
__global__ __launch_bounds__(256) void csrfin(const int2* __restrict__ pairs, const int* __restrict__ bko,
                                              int N, int E, int* __restrict__ rowptr, int* __restrict__ col) {
    __shared__ int cnt[NPB], pos[NPB];
    __shared__ int wsum[4];
    const int tid = threadIdx.x;
    const int b = blockIdx.x;
    const int nb = b << SH;
    const int beg = bko[b], end = bko[b + 1];
    for (int i = tid; i < NPB; i += 256) cnt[i] = 0;
    __syncthreads();
    for (int i = beg + tid; i < end; i += 256) atomicAdd(&cnt[pairs[i].y - nb], 1);
    __syncthreads();
    // exclusive scan cnt -> pos
    int lane = tid & 63, wave = tid >> 6;
    if (NPB == 512) {
        int a = cnt[2 * tid], b2 = cnt[2 * tid + 1];
        int s = a + b2, incl = s;
#pragma unroll
        for (int off = 1; off < 64; off <<= 1) { int u = __shfl_up(incl, off); if (lane >= off) incl += u; }
        if (lane == 63) wsum[wave] = incl;
        __syncthreads();
        int woff = 0;
        for (int w = 0; w < wave; ++w) woff += wsum[w];
        int ex = woff + incl - s;
        pos[2 * tid] = ex; pos[2 * tid + 1] = ex + a;
    } else {
        if (tid < NPB) {
            int a = cnt[tid], incl = a;
#pragma unroll
            for (int off = 1; off < 64; off <<= 1) { int u = __shfl_up(incl, off); if (lane >= off) incl += u; }
            pos[tid] = incl - a;
        }
    }
    __syncthreads();
    for (int i = tid; i < NPB; i += 256) {
        int node = nb + i;
        if (node < N) rowptr[node] = beg + pos[i];
    }
    if (b == gridDim.x - 1 && tid == 0) rowptr[N] = E;
    __syncthreads();
    for (int i = beg + tid; i < end; i += 256) {
        int2 pr = pairs[i];
        int p = atomicAdd(&pos[pr.y - nb], 1);
        col[beg + p] = pr.x;
    }
}

// ---------------- mean aggregation (CSR gather, bf16, forced 4-wide MLP) ----------------
// one wave per dst node, two 32-lane halves; half h takes runs of 4 edges at
// beg + 8k + 4h; 4 independent accumulator sets keep 4 loads in flight.
__global__ __launch_bounds__(256) void agg_bf16(const unsigned short* __restrict__ srcFeat,
                                                const int* __restrict__ rowptr,
                                                const int* __restrict__ col,
                                                unsigned short* __restrict__ outp, int n) {
    int w = (blockIdx.x << 2) + (threadIdx.x >> 6);
    if (w >= n) return;
    int lane = threadIdx.x & 63;
    int half = lane >> 5, l5 = lane & 31;
    int beg = rowptr[w], end = rowptr[w + 1];
    int T = end - beg;
    int nb8 = T >> 3;
    const unsigned short* base = srcFeat + l5 * 8;
    float a0[8], a1[8], a2[8], a3[8];
#pragma unroll
    for (int j = 0; j < 8; ++j) { a0[j] = 0.f; a1[j] = 0.f; a2[j] = 0.f; a3[j] = 0.f; }
    const int* cp = col + beg + half * 4;
    for (int k = 0; k < nb8; ++k) {
        int c0 = cp[k * 8 + 0], c1 = cp[k * 8 + 1], c2 = cp[k * 8 + 2], c3 = cp[k * 8 + 3];
        s16x8 v0 = *reinterpret_cast<const s16x8*>(base + (size_t)c0 * DHID);
        s16x8 v1 = *reinterpret_cast<const s16x8*>(base + (size_t)c1 * DHID);
        s16x8 v2 = *reinterpret_cast<const s16x8*>(base + (size_t)c2 * DHID);
        s16x8 v3 = *reinterpret_cast<const s16x8*>(base + (size_t)c3 * DHID);
#pragma unroll
        for (int j = 0; j < 8; ++j) {
            a0[j] += bf2f((unsigned short)v0[j]);
            a1[j] += bf2f((unsigned short)v1[j]);
            a2[j] += bf2f((unsigned short)v2[j]);
            a3[j] += bf2f((unsigned short)v3[j]);
        }
    }
    for (int i = beg + nb8 * 8 + half; i < end; i += 2) {
        int c = col[i];
        s16x8 v = *reinterpret_cast<const s16x8*>(base + (size_t)c * DHID);
#pragma unroll
        for (int j = 0; j < 8; ++j) a0[j] += bf2f((unsigned short)v[j]);
    }
    int deg = T > 0 ? T : 1;
    float inv = 1.0f / (float)deg;
    s16x8 o;
#pragma unroll
    for (int j = 0; j < 8; ++j) {
        float s = (a0[j] + a1[j]) + (a2[j] + a3[j]);
        s += __shfl_xor(s, 32);
        o[j] = (short)f2bf(s * inv);
    }
    if (half == 0)
        *reinterpret_cast<s16x8*>(outp + (size_t)w * DHID + l5 * 8) = o;
}

// ---------------- MFMA bf16 GEMM, N fixed at 256 ----------------
// BM=128, BN=256, BK=64, 512 threads (8 waves as 2x4), wave tile 64x64.
// LDS: linear rows of 128 B, content granule-swizzled via pre-swizzled source.
__device__ __forceinline__ unsigned swz(unsigned r, unsigned cb) {
    return r * 128u + (cb ^ ((r & 7u) << 4));
}

template<int KP>
__device__ __forceinline__ void mfma_pass(const unsigned short* A, const unsigned short* Wt,
                                          int m0, int M, int tid, int lane, int wr, int wc,
                                          f32x4 (&acc)[4][4], char* AsB, char* BsB) {
    const int wave = tid >> 6;
    for (int k0 = 0; k0 < KP; k0 += 64) {
        __syncthreads();
#pragma unroll
        for (int i = 0; i < 2; ++i) {
            int u = wave * 2 + i;
            int r = u * 8 + (lane >> 3);
            int gr = m0 + r; if (gr >= M) gr = M - 1;
            int gs = (lane & 7) ^ (r & 7);
            gld16(A + (size_t)gr * KP + k0 + gs * 8, AsB + u * 1024);
        }
#pragma unroll
        for (int i = 0; i < 4; ++i) {
            int u = wave * 4 + i;
            int nn = u * 8 + (lane >> 3);
            int gs = (lane & 7) ^ (nn & 7);
            gld16(Wt + (size_t)nn * KP + k0 + gs * 8, BsB + u * 1024);
        }
        __syncthreads();
#pragma unroll
        for (int kk = 0; kk < 2; ++kk) {
            s16x8 ar[4], br[4];
            unsigned colb = (unsigned)(kk * 64 + (lane >> 4) * 16);
#pragma unroll
            for (int mf = 0; mf < 4; ++mf)
                ar[mf] = *reinterpret_cast<const s16x8*>(AsB + swz((unsigned)(wr * 64 + mf * 16 + (lane & 15)), colb));
#pragma unroll
            for (int nf = 0; nf < 4; ++nf)
                br[nf] = *reinterpret_cast<const s16x8*>(BsB + swz((unsigned)(wc * 64 + nf * 16 + (lane & 15)), colb));
#pragma unroll
            for (int mf = 0; mf < 4; ++mf)
#pragma unroll
                for (int nf = 0; nf < 4; ++nf)
                    acc[mf][nf] = __builtin_amdgcn_mfma_f32_16x16x32_bf16(ar[mf], br[nf], acc[mf][nf], 0, 0, 0);
        }
    }
}

template<int K1, int ACT, int FUSE>  // ACT: 0 none, 1 relu, 2 leaky(0.01)
__global__ __launch_bounds__(512) void mgemm(const unsigned short* A1, const unsigned short* W1t,
                                             const float* __restrict__ bias,
                                             const unsigned short* A2, const unsigned short* W2t,
                                             unsigned short* outp, int M) {
    __shared__ char AsB[128 * 64 * 2];
    __shared__ char BsB[256 * 64 * 2];
    const int tid = threadIdx.x;
    const int lane = tid & 63, wave = tid >> 6;
    const int wr = wave >> 2, wc = wave & 3;
    const int m0 = blockIdx.x * 128;
    f32x4 acc[4][4];
#pragma unroll
    for (int a = 0; a < 4; ++a)
#pragma unroll
        for (int b = 0; b < 4; ++b) acc[a][b] = (f32x4)0.0f;

    mfma_pass<K1>(A1, W1t, m0, M, tid, lane, wr, wc, acc, AsB, BsB);
    if (FUSE) mfma_pass<DHID>(A2, W2t, m0, M, tid, lane, wr, wc, acc, AsB, BsB);

    const int col0 = wc * 64 + (lane & 15);
    float bc[4];
#pragma unroll
    for (int nf = 0; nf < 4; ++nf) bc[nf] = bias[col0 + nf * 16];
#pragma unroll
    for (int mf = 0; mf < 4; ++mf) {
        int row = m0 + wr * 64 + mf * 16 + (lane >> 4) * 4;
#pragma unroll
        for (int j = 0; j < 4; ++j) {
            if (row + j < M) {
#pragma unroll
                for (int nf = 0; nf < 4; ++nf) {
                    float v = acc[mf][nf][j] + bc[nf];
                    if (ACT == 1) v = fmaxf(v, 0.0f);
                    else if (ACT == 2) v = v > 0.0f ? v : 0.01f * v;
                    outp[(size_t)(row + j) * DHID + col0 + nf * 16] = f2bf(v);
                }
            }
        }
    }
}

// final projection [M,256]bf16 @ [256,2]f32 + b ; one wave per row
__global__ __launch_bounds__(256) void head_k(const unsigned short* __restrict__ f, const float* __restrict__ W,
                                              const float* __restrict__ b, float* __restrict__ outp, int M) {
    int row = blockIdx.x * 4 + (threadIdx.x >> 6);
    if (row >= M) return;
    int lane = threadIdx.x & 63;
    ushort4 v = *reinterpret_cast<const ushort4*>(f + (size_t)row * DHID + lane * 4);
    float4 w0 = *reinterpret_cast<const float4*>(W + lane * 8);
    float4 w1 = *reinterpret_cast<const float4*>(W + lane * 8 + 4);
    float a0 = bf2f(v.x) * w0.x + bf2f(v.y) * w0.z + bf2f(v.z) * w1.x + bf2f(v.w) * w1.z;
    float a1 = bf2f(v.x) * w0.y + bf2f(v.y) * w0.w + bf2f(v.z) * w1.y + bf2f(v.w) * w1.w;
#pragma unroll
    for (int off = 32; off > 0; off >>= 1) {
        a0 += __shfl_down(a0, off);
        a1 += __shfl_down(a1, off);
    }
    if (lane == 0) {
        outp[(size_t)row * 2 + 0] = a0 + b[0];
        outp[(size_t)row * 2 + 1] = a1 + b[1];
    }
}

extern "C" void kernel_launch(void* const* d_in, const int* in_sizes, int n_in,
                              void* d_out, int out_size, void* d_ws, size_t ws_size,
                              hipStream_t stream) {
    const float* x_host  = (const float*)d_in[0];
    const float* x_flow  = (const float*)d_in[1];
    const int*   hf_src  = (const int*)d_in[2];
    const int*   hf_dst  = (const int*)d_in[3];
    const int*   fh_src  = (const int*)d_in[4];
    const int*   fh_dst  = (const int*)d_in[5];
    const float* host_W  = (const float*)d_in[6];
    const float* host_b  = (const float*)d_in[7];
    const float* flow_W  = (const float*)d_in[8];
    const float* flow_b  = (const float*)d_in[9];
    const float* Wl_hf   = (const float*)d_in[10];
    const float* bl_hf   = (const float*)d_in[11];
    const float* Wr_hf   = (const float*)d_in[12];
    const float* Wl_fh   = (const float*)d_in[13];
    const float* bl_fh   = (const float*)d_in[14];
    const float* Wr_fh   = (const float*)d_in[15];
    const float* lin_W   = (const float*)d_in[16];
    const float* lin_b   = (const float*)d_in[17];

    char* ws = (char*)d_ws;
    size_t off = 0;
    auto alloc = [&](size_t bytes) -> char* {
        char* p = ws + off;
        off += (bytes + 255) & ~(size_t)255;
        return p;
    };
    typedef unsigned short u16;
    u16* F     = (u16*)alloc((size_t)NF * DHID * 2);
    u16* H     = (u16*)alloc((size_t)NH * DHID * 2);
    u16* AggH  = (u16*)alloc((size_t)NH * DHID * 2);
    u16* Xf    = (u16*)alloc((size_t)NF * DFLOW * 2);
    u16* Xh    = (u16*)alloc((size_t)NH * DHOST * 2);
    u16* hostWt = (u16*)alloc((size_t)DHID * DHOST * 2);
    u16* flowWt = (u16*)alloc((size_t)DHID * DFLOW * 2);
    u16* WlhfT  = (u16*)alloc((size_t)NLAYER * DHID * DHID * 2);
    u16* WrhfT  = (u16*)alloc((size_t)NLAYER * DHID * DHID * 2);
    u16* WlfhT  = (u16*)alloc((size_t)NLAYER * DHID * DHID * 2);
    u16* WrfhT  = (u16*)alloc((size_t)NLAYER * DHID * DHID * 2);
    int* rp_hf  = (int*)alloc((size_t)(NF + 1) * 4);
    int* col_hf = (int*)alloc((size_t)NE * 4);
    int* rp_fh  = (int*)alloc((size_t)(NH + 1) * 4);
    int* col_fh = (int*)alloc((size_t)NE * 4);
    int2* pairs = (int2*)alloc((size_t)NE * 8);     // shared between the two builds
    int* gbh    = (int*)alloc(512 * 4);
    int* bko    = (int*)alloc(513 * 4);
    int* gcur   = (int*)alloc(512 * 4);
    int* junk   = (int*)alloc(4);

    size_t avail = (ws_size > off) ? (ws_size - off) : 0;
    long long ch = (long long)(avail / ((size_t)DHID * 2)) - 128;
    if (ch < 128) ch = 128;
    if (ch > NF) ch = NF;
    int CH = (int)(ch & ~127LL);
    if (CH < 128) CH = 128;
    u16* AggC = (u16*)alloc((size_t)CH * DHID * 2);

    // bucket geometry: hf graph (dst<NF): 512 nodes/bucket; fh graph (dst<NH): 64 nodes/bucket
    const int NBKT_HF = (NF + 511) / 512;   // 391
    const int NBKT_FH = (NH + 63) / 64;     // 313

    // ---- CSR build: hf (host -> flow) ----
    zero_k<<<2, 256, 0, stream>>>(gbh, NBKT_HF);
    histA<9, 391><<<(NE + 2047) / 2048, 256, 0, stream>>>(hf_dst, NE, gbh);
    scan1_k<<<1, 256, 0, stream>>>(gbh, NBKT_HF, bko, junk);
    initcur_k<<<2, 256, 0, stream>>>(bko, gcur, NBKT_HF, NE);
    binpass<9, 391, 8192><<<(NE + 8191) / 8192, 256, 0, stream>>>(hf_src, hf_dst, NE, gcur, pairs);
    csrfin<9, 512><<<NBKT_HF, 256, 0, stream>>>(pairs, bko, NF, NE, rp_hf, col_hf);

    // ---- CSR build: fh (flow -> host) ----
    zero_k<<<2, 256, 0, stream>>>(gbh, NBKT_FH);
    histA<6, 313><<<(NE + 2047) / 2048, 256, 0, stream>>>(fh_dst, NE, gbh);
    scan1_k<<<1, 256, 0, stream>>>(gbh, NBKT_FH, bko, junk);
    initcur_k<<<2, 256, 0, stream>>>(bko, gcur, NBKT_FH, NE);
    binpass<6, 313, 8192><<<(NE + 8191) / 8192, 256, 0, stream>>>(fh_src, fh_dst, NE, gcur, pairs);
    csrfin<6, 64><<<NBKT_FH, 256, 0, stream>>>(pairs, bko, NH, NE, rp_fh, col_fh);

    // ---- convert inputs / weights to bf16 ----
    cvt_bf16_k<<<(NH * DHOST / 4 + 255) / 256, 256, 0, stream>>>(x_host, Xh, NH * DHOST / 4);
    cvt_bf16_k<<<(NF * DFLOW / 4 + 255) / 256, 256, 0, stream>>>(x_flow, Xf, NF * DFLOW / 4);
    tpose_k<<<dim3(8, DHOST / 32), 256, 0, stream>>>(host_W, hostWt, DHOST);
    tpose_k<<<dim3(8, DFLOW / 32), 256, 0, stream>>>(flow_W, flowWt, DFLOW);
    for (int i = 0; i < NLAYER; ++i) {
        size_t wo = (size_t)i * DHID * DHID;
        tpose_k<<<dim3(8, 8), 256, 0, stream>>>(Wl_hf + wo, WlhfT + wo, DHID);
        tpose_k<<<dim3(8, 8), 256, 0, stream>>>(Wr_hf + wo, WrhfT + wo, DHID);
        tpose_k<<<dim3(8, 8), 256, 0, stream>>>(Wl_fh + wo, WlfhT + wo, DHID);
        tpose_k<<<dim3(8, 8), 256, 0, stream>>>(Wr_fh + wo, WrfhT + wo, DHID);
    }

    // ---- input projections (relu) ----
    mgemm<DHOST, 1, 0><<<(NH + 127) / 128, 512, 0, stream>>>(Xh, hostWt, host_b, Xh, hostWt, H, NH);
    mgemm<DFLOW, 1, 0><<<(NF + 127) / 128, 512, 0, stream>>>(Xf, flowWt, flow_b, Xf, flowWt, F, NF);

    // ---- SAGE layers (in-place feature updates; both sides consume OLD h,f) ----
    for (int i = 0; i < NLAYER; ++i) {
        const u16* wl_hf = WlhfT + (size_t)i * DHID * DHID;
        const u16* wr_hf = WrhfT + (size_t)i * DHID * DHID;
        const u16* wl_fh = WlfhT + (size_t)i * DHID * DHID;
        const u16* wr_fh = WrfhT + (size_t)i * DHID * DHID;
        const float* b_hf = bl_hf + (size_t)i * DHID;
        const float* b_fh = bl_fh + (size_t)i * DHID;

        // 1) host-side aggregation from OLD f (must precede any F overwrite)
        agg_bf16<<<(NH + 3) / 4, 256, 0, stream>>>(F, rp_fh, col_fh, AggH, NH);

        // 2) flow update, chunked: agg from OLD h, then in-place fused gemm on F rows
        for (int c0 = 0; c0 < NF; c0 += CH) {
            int rows = NF - c0; if (rows > CH) rows = CH;
            agg_bf16<<<(rows + 3) / 4, 256, 0, stream>>>(H, rp_hf + c0, col_hf, AggC, rows);
            mgemm<DHID, 2, 1><<<(rows + 127) / 128, 512, 0, stream>>>(AggC, wl_hf, b_hf,
                                                                      F + (size_t)c0 * DHID, wr_hf,
                                                                      F + (size_t)c0 * DHID, rows);
        }

        // 3) host update, in-place on H (uses OLD h as root)
        mgemm<DHID, 2, 1><<<(NH + 127) / 128, 512, 0, stream>>>(AggH, wl_fh, b_fh, H, wr_fh, H, NH);
    }

    // ---- output head ----
    head_k<<<(NF + 3) / 4, 256, 0, stream>>>(F, lin_W, lin_b, (float*)d_out, NF);
}